// Round 1
// baseline (751.423 us; speedup 1.0000x reference)
//
#include <hip/hip_runtime.h>
#include <math.h>

#define BB 4
#define TT 2048
#define FIN 512
#define DD 128
#define NC 32          // chunks along T
#define CT 64          // timesteps per chunk (NC*CT == TT)
#define ROWS (BB*TT)   // 8192
#define CLAMP_V 1e20f
#define EPS_LN_ 1e-5f
#define EPS_DEN_ 1e-5f

// ---------------- k0: per-row LayerNorm stats (mu, rstd) ----------------
__global__ __launch_bounds__(256) void k0_stats(const float* __restrict__ h,
                                                float* __restrict__ stats) {
  int wv = threadIdx.x >> 6, lane = threadIdx.x & 63;
  int row = blockIdx.x * 4 + wv;
  const float* hr = h + (size_t)row * FIN;
  float s = 0.f, sq = 0.f;
#pragma unroll
  for (int j = 0; j < FIN / 64; ++j) {
    float v = hr[lane + 64 * j];
    s += v; sq += v * v;
  }
#pragma unroll
  for (int m = 32; m >= 1; m >>= 1) {
    s += __shfl_xor(s, m);
    sq += __shfl_xor(sq, m);
  }
  if (lane == 0) {
    float mu = s * (1.f / FIN);
    float var = sq * (1.f / FIN) - mu * mu;
    stats[row * 2] = mu;
    stats[row * 2 + 1] = rsqrtf(var + EPS_LN_);
  }
}

// ---------------- k1: fused LN + GEMM -> K(phi), Q(phi), V, SC ----------------
// M=8192, K=512, N=128 per weight; grid (64 row-tiles, 4 weights)
__global__ __launch_bounds__(256) void k1_lngemm(
    const float* __restrict__ h, const float* __restrict__ stats,
    const float* __restrict__ ln_g, const float* __restrict__ ln_b,
    const float* __restrict__ Wk, const float* __restrict__ Wq,
    const float* __restrict__ Wv, const float* __restrict__ Wsc,
    float* __restrict__ Kb, float* __restrict__ Qb,
    float* __restrict__ Vb, float* __restrict__ SCb) {
  __shared__ float As[32 * 129];  // [k][r], padded stride 129
  __shared__ float Bs[32 * 128];  // [k][n]
  int tid = threadIdx.x;
  int row0 = blockIdx.x * 128;
  int wsel = blockIdx.y;
  const float* W = (wsel == 0) ? Wk : (wsel == 1) ? Wq : (wsel == 2) ? Wv : Wsc;
  float* Ob = (wsel == 0) ? Kb : (wsel == 1) ? Qb : (wsel == 2) ? Vb : SCb;
  int ty = tid >> 4, tx = tid & 15;
  float acc[8][8];
#pragma unroll
  for (int i = 0; i < 8; ++i)
#pragma unroll
    for (int j = 0; j < 8; ++j) acc[i][j] = 0.f;

  for (int ks = 0; ks < FIN; ks += 32) {
#pragma unroll
    for (int j = 0; j < 16; ++j) {   // stage A (LN applied on the fly)
      int idx = tid + 256 * j;       // 4096 = 128r x 32f
      int r = idx >> 5, f = idx & 31;
      float v = h[(size_t)(row0 + r) * FIN + ks + f];
      float mu = stats[(row0 + r) * 2], rs = stats[(row0 + r) * 2 + 1];
      As[f * 129 + r] = (v - mu) * rs * ln_g[ks + f] + ln_b[ks + f];
    }
#pragma unroll
    for (int j = 0; j < 16; ++j) {   // stage B
      int idx = tid + 256 * j;       // 32k x 128n
      int k = idx >> 7, n = idx & 127;
      Bs[k * 128 + n] = W[(size_t)(ks + k) * DD + n];
    }
    __syncthreads();
#pragma unroll
    for (int k = 0; k < 32; ++k) {
      float a[8], bv[8];
#pragma unroll
      for (int i = 0; i < 8; ++i) a[i] = As[k * 129 + ty * 8 + i];
#pragma unroll
      for (int j = 0; j < 8; ++j) bv[j] = Bs[k * 128 + tx * 8 + j];
#pragma unroll
      for (int i = 0; i < 8; ++i)
#pragma unroll
        for (int j = 0; j < 8; ++j) acc[i][j] = fmaf(a[i], bv[j], acc[i][j]);
    }
    __syncthreads();
  }
  bool phi = (wsel < 2);
#pragma unroll
  for (int i = 0; i < 8; ++i) {
    int row = row0 + ty * 8 + i;
#pragma unroll
    for (int j = 0; j < 8; ++j) {
      float z = acc[i][j];
      if (phi) z = (z > 0.f) ? (z + 1.f) : expf(z);   // elu(z)+1
      Ob[(size_t)row * DD + tx * 8 + j] = z;
    }
  }
}

// ---------------- k2: per-chunk KV outer-product sums + K sums ----------------
__global__ __launch_bounds__(256) void k2_chunksum(const float* __restrict__ Kb,
                                                   const float* __restrict__ Vb,
                                                   float* __restrict__ kvsum,
                                                   float* __restrict__ ksum) {
  int bc = blockIdx.x;            // b*NC + c
  int b = bc >> 5, c = bc & 31;
  __shared__ float Kc[CT * 128];
  __shared__ float Vc[CT * 128];
  int tid = threadIdx.x;
  size_t base = (size_t)(b * TT + c * CT) * 128;
#pragma unroll
  for (int j = 0; j < 32; ++j) {
    int idx = tid + 256 * j;
    Kc[idx] = Kb[base + idx];
    Vc[idx] = Vb[base + idx];
  }
  __syncthreads();
  int ti = tid >> 4, tl = tid & 15;
  int i0 = ti * 8, l0 = tl * 8;
  float acc[8][8];
#pragma unroll
  for (int i = 0; i < 8; ++i)
#pragma unroll
    for (int j = 0; j < 8; ++j) acc[i][j] = 0.f;
  for (int t = 0; t < CT; ++t) {
    float kk[8], vv[8];
#pragma unroll
    for (int i = 0; i < 8; ++i) kk[i] = Kc[t * 128 + i0 + i];
#pragma unroll
    for (int j = 0; j < 8; ++j) vv[j] = Vc[t * 128 + l0 + j];
#pragma unroll
    for (int i = 0; i < 8; ++i)
#pragma unroll
      for (int j = 0; j < 8; ++j) acc[i][j] = fmaf(kk[i], vv[j], acc[i][j]);
  }
  size_t ob = (size_t)bc * 16384;
#pragma unroll
  for (int i = 0; i < 8; ++i)
#pragma unroll
    for (int j = 0; j < 8; ++j)
      kvsum[ob + (size_t)(i0 + i) * 128 + l0 + j] = acc[i][j];
  if (tid < 128) {
    float s = 0.f;
    for (int t = 0; t < CT; ++t) s += Kc[t * 128 + tid];
    ksum[bc * 128 + tid] = s;
  }
}

// ---------------- k3: in-place exclusive prefix over chunks (KV state) ----------------
__global__ __launch_bounds__(256) void k3_prefix(float* __restrict__ kvsum) {
  int gid = blockIdx.x * 256 + threadIdx.x;  // 65536 = B*128*128
  int b = gid >> 14, rem = gid & 16383;
  size_t base = (size_t)b * NC * 16384 + rem;
  float run = 0.f;
  for (int c = 0; c < NC; ++c) {
    size_t idx = base + (size_t)c * 16384;
    float t = kvsum[idx];
    kvsum[idx] = run;
    run += t;
  }
}

// ---------------- k4: Z = clamp(cumsum K) + Z0 ----------------
__global__ __launch_bounds__(128) void k4_z(const float* __restrict__ Kb,
                                            const float* __restrict__ ksum,
                                            const float* __restrict__ Z0,
                                            float* __restrict__ Zout) {
  int bc = blockIdx.x; int b = bc >> 5, c = bc & 31;
  int i = threadIdx.x;
  float z = 0.f;
  for (int cc = 0; cc < c; ++cc) z += ksum[(b * NC + cc) * 128 + i];
  float z0 = Z0[b * 128 + i];
#pragma unroll 4
  for (int t = 0; t < CT; ++t) {
    int gt = c * CT + t;
    z += Kb[(size_t)(b * TT + gt) * 128 + i];
    float zc = fminf(fmaxf(z, -CLAMP_V), CLAMP_V) + z0;
    Zout[(size_t)(b * TT + gt) * 128 + i] = zc;
  }
}

// ---------------- k5: den = Q . Z + eps ----------------
__global__ __launch_bounds__(256) void k5_den(const float* __restrict__ Qb,
                                              const float* __restrict__ Zout,
                                              float* __restrict__ den) {
  int wv = threadIdx.x >> 6, lane = threadIdx.x & 63;
  int row = blockIdx.x * 4 + wv;
  size_t o = (size_t)row * 128;
  float p = Qb[o + lane] * Zout[o + lane] + Qb[o + 64 + lane] * Zout[o + 64 + lane];
#pragma unroll
  for (int m = 32; m >= 1; m >>= 1) p += __shfl_xor(p, m);
  if (lane == 0) den[row] = p + EPS_DEN_;
}

// ---------------- k6: main pass — S stream + numerator partials ----------------
// grid (2 l-halves, NC chunks, B batches); block 256 = 4 waves
// wave w owns i in [32w,32w+32); lane = l within the 64-wide l-half
__global__ __launch_bounds__(256) void k6_main(
    const float* __restrict__ Kb, const float* __restrict__ Qb,
    const float* __restrict__ Vb, const float* __restrict__ kvpref,
    const float* __restrict__ S0, float* __restrict__ Sout,
    float* __restrict__ numpart) {
  __shared__ float KQ[CT * 128 * 2];  // 64 KiB, [t][i][{k,q}]
  int tid = threadIdx.x;
  int lhalf = blockIdx.x, c = blockIdx.y, b = blockIdx.z;
  int w = tid >> 6, lane = tid & 63;
  int i0 = w * 32;
  int l = lhalf * 64 + lane;
  size_t rowbase = (size_t)(b * TT + c * CT) * 128;
#pragma unroll
  for (int j = 0; j < 32; ++j) {
    int idx = tid + 256 * j;          // t*128 + i
    KQ[idx * 2] = Kb[rowbase + idx];
    KQ[idx * 2 + 1] = Qb[rowbase + idx];
  }
  float s[32], s0[32];
  int bc = b * NC + c;
#pragma unroll
  for (int ii = 0; ii < 32; ++ii) {
    s[ii] = kvpref[(size_t)bc * 16384 + (size_t)(i0 + ii) * 128 + l];
    s0[ii] = S0[((size_t)b * 128 + i0 + ii) * 128 + l];
  }
  __syncthreads();
  for (int t = 0; t < CT; ++t) {
    int gt = c * CT + t;
    float v = Vb[(size_t)(b * TT + gt) * 128 + l];
    float num = 0.f;
    size_t sb = ((size_t)(b * TT + gt) * 128 + i0) * 128 + l;
#pragma unroll
    for (int ii = 0; ii < 32; ++ii) {
      float2 kq = *(const float2*)&KQ[(t * 128 + i0 + ii) * 2];
      s[ii] = fmaf(kq.x, v, s[ii]);
      float sc = fminf(fmaxf(s[ii], -CLAMP_V), CLAMP_V) + s0[ii];
      __builtin_nontemporal_store(sc, &Sout[sb + (size_t)ii * 128]);
      num = fmaf(kq.y, sc, num);
    }
    numpart[(size_t)w * ROWS * 128 + (size_t)(b * TT + gt) * 128 + l] = num;
  }
}

// ---------------- k7: combine numerator + FF + shortcut ----------------
__global__ __launch_bounds__(256) void k7_ff(
    const float* __restrict__ numpart, const float* __restrict__ den,
    const float* __restrict__ w1, const float* __restrict__ b1,
    const float* __restrict__ w2, const float* __restrict__ b2,
    const float* __restrict__ SCb, const float* __restrict__ sc_b,
    float* __restrict__ out) {
  __shared__ float a[64 * 128];
  __shared__ float h1[64 * 128];
  int tid = threadIdx.x;
  int row0 = blockIdx.x * 64;
#pragma unroll
  for (int j = 0; j < 32; ++j) {
    int idx = tid + 256 * j;  // r*128 + l
    int r = idx >> 7;
    size_t g = (size_t)(row0 + r) * 128 + (idx & 127);
    float s = numpart[g] + numpart[g + (size_t)ROWS * 128] +
              numpart[g + 2 * (size_t)ROWS * 128] + numpart[g + 3 * (size_t)ROWS * 128];
    a[idx] = s / den[row0 + r];
  }
  __syncthreads();
  int l = tid & 127, half = tid >> 7;
  for (int rc = 0; rc < 4; ++rc) {        // layer 1
    int r0 = half * 32 + rc * 8;
    float acc[8];
#pragma unroll
    for (int rr = 0; rr < 8; ++rr) acc[rr] = b1[l];
    for (int k = 0; k < 128; ++k) {
      float wv = w1[k * 128 + l];
#pragma unroll
      for (int rr = 0; rr < 8; ++rr) acc[rr] = fmaf(a[(r0 + rr) * 128 + k], wv, acc[rr]);
    }
#pragma unroll
    for (int rr = 0; rr < 8; ++rr) h1[(r0 + rr) * 128 + l] = fmaxf(acc[rr], 0.f);
  }
  __syncthreads();
  for (int rc = 0; rc < 4; ++rc) {        // layer 2 + relu + shortcut
    int r0 = half * 32 + rc * 8;
    float acc[8];
#pragma unroll
    for (int rr = 0; rr < 8; ++rr) acc[rr] = b2[l];
    for (int k = 0; k < 128; ++k) {
      float wv = w2[k * 128 + l];
#pragma unroll
      for (int rr = 0; rr < 8; ++rr) acc[rr] = fmaf(h1[(r0 + rr) * 128 + k], wv, acc[rr]);
    }
#pragma unroll
    for (int rr = 0; rr < 8; ++rr) {
      int row = row0 + r0 + rr;
      out[(size_t)row * 128 + l] =
          fmaxf(acc[rr], 0.f) + SCb[(size_t)row * 128 + l] + sc_b[l];
    }
  }
}

extern "C" void kernel_launch(void* const* d_in, const int* in_sizes, int n_in,
                              void* d_out, int out_size, void* d_ws, size_t ws_size,
                              hipStream_t stream) {
  const float* history = (const float*)d_in[0];
  const float* S0   = (const float*)d_in[1];
  const float* Z0   = (const float*)d_in[2];
  const float* Wk   = (const float*)d_in[3];
  const float* Wq   = (const float*)d_in[4];
  const float* Wv   = (const float*)d_in[5];
  const float* ln_g = (const float*)d_in[6];
  const float* ln_b = (const float*)d_in[7];
  const float* w1   = (const float*)d_in[8];
  const float* b1   = (const float*)d_in[9];
  const float* w2   = (const float*)d_in[10];
  const float* b2   = (const float*)d_in[11];
  const float* sc_w = (const float*)d_in[12];
  const float* sc_b = (const float*)d_in[13];

  float* out  = (float*)d_out;                       // [B,T,D]
  float* Sout = out + (size_t)ROWS * DD;             // [B,T,D,D]
  float* Zout = Sout + (size_t)ROWS * DD * DD;       // [B,T,D]

  float* ws = (float*)d_ws;
  float* stats   = ws;                    // 16384
  float* Kb      = stats + 16384;         // 1048576
  float* Qb      = Kb + (size_t)ROWS * DD;
  float* Vb      = Qb + (size_t)ROWS * DD;
  float* SCb     = Vb + (size_t)ROWS * DD;
  float* kvsum   = SCb + (size_t)ROWS * DD;          // 2097152
  float* ksum    = kvsum + (size_t)BB * NC * 16384;  // 16384
  float* numpart = ksum + BB * NC * 128;             // 4194304
  float* den     = numpart + 4 * (size_t)ROWS * DD;  // 8192

  k0_stats<<<ROWS / 4, 256, 0, stream>>>(history, stats);
  k1_lngemm<<<dim3(ROWS / 128, 4), 256, 0, stream>>>(history, stats, ln_g, ln_b,
                                                     Wk, Wq, Wv, sc_w,
                                                     Kb, Qb, Vb, SCb);
  k2_chunksum<<<BB * NC, 256, 0, stream>>>(Kb, Vb, kvsum, ksum);
  k3_prefix<<<(BB * DD * DD) / 256, 256, 0, stream>>>(kvsum);
  k4_z<<<BB * NC, 128, 0, stream>>>(Kb, ksum, Z0, Zout);
  k5_den<<<ROWS / 4, 256, 0, stream>>>(Qb, Zout, den);
  k6_main<<<dim3(2, NC, BB), 256, 0, stream>>>(Kb, Qb, Vb, kvsum, S0, Sout, numpart);
  k7_ff<<<ROWS / 64, 256, 0, stream>>>(numpart, den, w1, b1, w2, b2, SCb, sc_b, out);
}